// Round 5
// baseline (4461.970 us; speedup 1.0000x reference)
//
#include <hip/hip_runtime.h>
#include <math.h>

// Problem constants (fixed by setup_inputs)
constexpr int B  = 8;
constexpr int D  = 512;
constexpr int T  = 4096;
constexpr int N  = 9;
constexpr int CS = 1024;
constexpr int CD = 8;

constexpr int TT  = 16;   // columns per block
constexpr int CPW = 4;    // columns per wave
constexpr int NBLK = 2048;

#define WN_EPS 1e-12

// ---------------- workspace layout (doubles) ----------------
// w_in_n  [N][CD][D]   : 36864
// w_out_n [N][D][CD]   : 36864
// cb_n    [N][CS][CD]  : 73728
// cb_sq   [N][CS]      : 9216
// loss partials at ws+160000 : NBLK doubles

__global__ void rvq_prep(const float* __restrict__ in_v,
                         const float* __restrict__ in_g,
                         const float* __restrict__ out_v,
                         const float* __restrict__ out_g,
                         const float* __restrict__ cb,
                         double* __restrict__ ws) {
    double* w_in_n  = ws;
    double* w_out_n = ws + N * CD * D;
    double* cb_n    = ws + 2 * N * CD * D;
    double* cb_sq   = cb_n + N * CS * CD;

    int blk = blockIdx.x;
    int tid = threadIdx.x;

    if (blk == 0) {
        int row = tid;                       // 72 rows of length 512
        if (row < N * CD) {
            const float* v = in_v + (size_t)row * D;
            double s = 0.0;
            for (int j = 0; j < D; ++j) { double x = (double)v[j]; s += x * x; }
            double denom = fmax(sqrt(s), WN_EPS);
            double g = (double)in_g[row];
            for (int j = 0; j < D; ++j)
                w_in_n[(size_t)row * D + j] = (g * (double)v[j]) / denom;
        }
    } else if (blk <= 18) {
        int row = (blk - 1) * 256 + tid;     // 4608 rows of length 8
        if (row < N * D) {
            const float* v = out_v + (size_t)row * CD;
            double s = 0.0;
            #pragma unroll
            for (int k = 0; k < CD; ++k) { double x = (double)v[k]; s += x * x; }
            double denom = fmax(sqrt(s), WN_EPS);
            double g = (double)out_g[row];
            #pragma unroll
            for (int k = 0; k < CD; ++k)
                w_out_n[(size_t)row * CD + k] = (g * (double)v[k]) / denom;
        }
    } else {
        int row = (blk - 19) * 256 + tid;    // 9216 rows of length 8
        if (row < N * CS) {
            const float* v = cb + (size_t)row * CD;
            double s = 0.0;
            #pragma unroll
            for (int k = 0; k < CD; ++k) { double x = (double)v[k]; s += x * x; }
            double denom = fmax(sqrt(s), WN_EPS);
            double sq = 0.0;
            #pragma unroll
            for (int k = 0; k < CD; ++k) {
                double e = (double)v[k] / denom;
                cb_n[(size_t)row * CD + k] = e;
                sq += e * e;
            }
            cb_sq[row] = sq;
        }
    }
}

// ---- cross-lane helpers (wave64); CTRL must be a literal ----
template<int CTRL>
__device__ inline double dpp_mov_f64(double x) {
    union { double d; int i[2]; } u, v;
    u.d = x;
    v.i[0] = __builtin_amdgcn_update_dpp(0, u.i[0], CTRL, 0xF, 0xF, false);
    v.i[1] = __builtin_amdgcn_update_dpp(0, u.i[1], CTRL, 0xF, 0xF, false);
    return v.d;
}
template<int CTRL>
__device__ inline int dpp_mov_i32(int x) {
    return __builtin_amdgcn_update_dpp(0, x, CTRL, 0xF, 0xF, false);
}
// full-wave sum, result in all lanes. Rounds: xor1, xor2, half-mirror (==xor4
// after quad rounds), mirror (==xor8), then shfl 16/32.
__device__ inline double wave_allsum_f64(double x) {
    x += dpp_mov_f64<0xB1>(x);   // quad_perm(1,0,3,2)
    x += dpp_mov_f64<0x4E>(x);   // quad_perm(2,3,0,1)
    x += dpp_mov_f64<0x141>(x);  // row_half_mirror
    x += dpp_mov_f64<0x140>(x);  // row_mirror
    x += __shfl_xor(x, 16, 64);
    x += __shfl_xor(x, 32, 64);
    return x;
}

template<int CTRL>
__device__ inline void argmin_round_dpp(double& bd, int& bi) {
    double od = dpp_mov_f64<CTRL>(bd);
    int    oi = dpp_mov_i32<CTRL>(bi);
    bool t = (od < bd) || (od == bd && oi < bi);
    bd = t ? od : bd;
    bi = t ? oi : bi;
}
__device__ inline void argmin_round_shfl(double& bd, int& bi, int off) {
    double od = __shfl_xor(bd, off, 64);
    int    oi = __shfl_xor(bi, off, 64);
    bool t = (od < bd) || (od == bd && oi < bi);
    bd = t ? od : bd;
    bi = t ? oi : bi;
}

// LDS codebook addressing: plane k at byte k*8192; element (c,k) at
// byte k*8192 + ((c*8) ^ ((k&3)<<5)). Bijective per plane; both the staging
// writes and the scan reads land on 16 distinct banks x 4 lanes = the b64 floor.
__device__ inline int cbl_off(int c, int k) {
    return k * 8192 + ((c * 8) ^ ((k & 3) << 5));
}

__global__ __launch_bounds__(256, 2)
void rvq_main(const float* __restrict__ z,
              const float* __restrict__ in_b,
              const float* __restrict__ out_b,
              const float* __restrict__ cb,
              const double* __restrict__ ws,
              double* __restrict__ wsl,
              float* __restrict__ out) {
    const double* w_in_n  = ws;
    const double* w_out_n = ws + N * CD * D;
    const double* cb_n    = ws + 2 * N * CD * D;
    const double* cb_sq   = cb_n + N * CS * CD;

    extern __shared__ char lds[];            // 65536 B dynamic
    float* zt = (float*)lds;                 // [512][17] f32 transpose scratch

    const int tid = threadIdx.x;
    const int l   = tid & 63;
    const int w   = tid >> 6;
    const int blk = blockIdx.x;              // 2048
    const int b   = blk >> 8;                // 256 blocks per batch
    const int t0  = (blk & 255) * TT;
    const int tw  = t0 + w * CPW;            // this wave's first column

    // ---- transpose z into zt (coalesced global reads) ----
    {
        const float* zb = z + (size_t)b * D * T + t0;
        for (int rr = 0; rr < 32; ++rr) {
            int e = rr * 256 + tid;
            int d = e >> 4, c = e & 15;
            zt[d * 17 + c] = zb[(size_t)d * T + c];
        }
    }
    __syncthreads();

    // ---- residual in registers: r[cc][j] holds d = l + 64*j of column tw+cc ----
    double r[CPW][8];
    #pragma unroll
    for (int cc = 0; cc < CPW; ++cc)
        #pragma unroll
        for (int j = 0; j < 8; ++j)
            r[cc][j] = (double)zt[(l + 64 * j) * 17 + (w * CPW + cc)];
    __syncthreads();   // zt dead; lds becomes the codebook buffer

    double ze[CD][CPW];
    double wloss = 0.0;

    float* codes_out = out + (size_t)B * D * T;
    float* lat_out   = codes_out + (size_t)B * N * T;

    for (int i = 0; i < N; ++i) {
        // ---- stage codebook (f64, swizzled) into LDS ----
        {
            const double* src = cb_n + (size_t)i * CS * CD;
            for (int rr = 0; rr < 32; ++rr) {
                int e = rr * 256 + tid;      // e = c*8 + k
                int c = e >> 3, k = e & 7;
                *(double*)(lds + cbl_off(c, k)) = src[e];
            }
        }
        __syncthreads();

        // ---- in-proj: z_e[k][col] = sum_d w_in[k][d] * r[d][col] + b ----
        const double* Wi = w_in_n + (size_t)i * CD * D;
        #pragma unroll
        for (int k = 0; k < CD; ++k) {
            const double* wk = Wi + (size_t)k * D + l;
            double p0 = 0.0, p1 = 0.0, p2 = 0.0, p3 = 0.0;
            #pragma unroll
            for (int j = 0; j < 8; ++j) {
                double wv = wk[64 * j];
                p0 = fma(wv, r[0][j], p0);
                p1 = fma(wv, r[1][j], p1);
                p2 = fma(wv, r[2][j], p2);
                p3 = fma(wv, r[3][j], p3);
            }
            double bias = (double)in_b[i * CD + k];
            ze[k][0] = wave_allsum_f64(p0) + bias;
            ze[k][1] = wave_allsum_f64(p1) + bias;
            ze[k][2] = wave_allsum_f64(p2) + bias;
            ze[k][3] = wave_allsum_f64(p3) + bias;
        }

        // ---- latents (lane 0 of each wave writes 8 float4) ----
        if (l == 0) {
            #pragma unroll
            for (int k = 0; k < CD; ++k) {
                float4 v = make_float4((float)ze[k][0], (float)ze[k][1],
                                       (float)ze[k][2], (float)ze[k][3]);
                *(float4*)&lat_out[((size_t)b * N * CD + (size_t)i * CD + k) * T + tw] = v;
            }
        }

        // ---- per-column normalize constants ----
        double es[CPW], m2i[CPW];
        #pragma unroll
        for (int cc = 0; cc < CPW; ++cc) {
            double s = 0.0;
            #pragma unroll
            for (int k = 0; k < CD; ++k) s = fma(ze[k][cc], ze[k][cc], s);
            double denom = fmax(sqrt(s), WN_EPS);
            double inv = 1.0 / denom;
            es[cc]  = s * inv * inv;
            m2i[cc] = -2.0 * inv;
        }

        // ---- distance scan: lane l covers codes l + 64*g ----
        const double* Cq = cb_sq + (size_t)i * CS;
        double best[CPW];
        int    bcode[CPW];
        #pragma unroll
        for (int cc = 0; cc < CPW; ++cc) { best[cc] = __builtin_inf(); bcode[cc] = 0; }
        for (int g = 0; g < 16; ++g) {
            int c = l + 64 * g;
            double row[CD];
            #pragma unroll
            for (int k = 0; k < CD; ++k)
                row[k] = *(const double*)(lds + cbl_off(c, k));
            double cq = Cq[c];
            #pragma unroll
            for (int cc = 0; cc < CPW; ++cc) {
                double dot = 0.0;
                #pragma unroll
                for (int k = 0; k < CD; ++k) dot = fma(ze[k][cc], row[k], dot);
                double dist = fma(m2i[cc], dot, es[cc]) + cq;
                bool take = (dist < best[cc]);   // ascending c within lane: first-min
                best[cc]  = take ? dist : best[cc];
                bcode[cc] = take ? c : bcode[cc];
            }
        }

        // ---- argmin butterfly across 64 lanes (first-min tie-break) ----
        #pragma unroll
        for (int cc = 0; cc < CPW; ++cc) {
            double bd = best[cc]; int bi = bcode[cc];
            argmin_round_dpp<0xB1>(bd, bi);
            argmin_round_dpp<0x4E>(bd, bi);
            argmin_round_dpp<0x141>(bd, bi);
            argmin_round_dpp<0x140>(bd, bi);
            argmin_round_shfl(bd, bi, 16);
            argmin_round_shfl(bd, bi, 32);
            best[cc] = bd; bcode[cc] = bi;
        }

        // ---- codes (lane 0, one float4 per wave) ----
        if (l == 0) {
            float4 v = make_float4((float)bcode[0], (float)bcode[1],
                                   (float)bcode[2], (float)bcode[3]);
            *(float4*)&codes_out[((size_t)b * N + i) * T + tw] = v;
        }

        // ---- gather raw code + loss + straight-through (q overwrites ze) ----
        const float* Cb = cb + (size_t)i * CS * CD;
        #pragma unroll
        for (int cc = 0; cc < CPW; ++cc) {
            int ui = __builtin_amdgcn_readfirstlane(bcode[cc]);
            const float* crow = Cb + (size_t)ui * CD;
            #pragma unroll
            for (int k = 0; k < CD; ++k) {
                double cv = (double)crow[k];
                double zv = ze[k][cc];
                double df = zv - cv;
                wloss = fma(df, df, wloss);
                ze[k][cc] = zv + (cv - zv);    // z_e + (z_q_i - z_e)
            }
        }

        // ---- out-proj + residual update ----
        const double* Wo = w_out_n + (size_t)i * D * CD;
        #pragma unroll
        for (int j = 0; j < 8; ++j) {
            int d = l + 64 * j;
            const double* wr = Wo + (size_t)d * CD;
            double w0 = wr[0], w1 = wr[1], w2 = wr[2], w3 = wr[3];
            double w4 = wr[4], w5 = wr[5], w6 = wr[6], w7 = wr[7];
            double bias = (double)out_b[i * D + d];
            #pragma unroll
            for (int cc = 0; cc < CPW; ++cc) {
                double o = 0.0;
                o = fma(w0, ze[0][cc], o);
                o = fma(w1, ze[1][cc], o);
                o = fma(w2, ze[2][cc], o);
                o = fma(w3, ze[3][cc], o);
                o = fma(w4, ze[4][cc], o);
                o = fma(w5, ze[5][cc], o);
                o = fma(w6, ze[6][cc], o);
                o = fma(w7, ze[7][cc], o);
                o += bias;
                r[cc][j] -= o;
            }
        }
        __syncthreads();   // everyone done with this stage's LDS codebook
    }

    // ---- final: r -> zt (f32), then coalesced z_q = z - r ----
    #pragma unroll
    for (int cc = 0; cc < CPW; ++cc)
        #pragma unroll
        for (int j = 0; j < 8; ++j)
            zt[(l + 64 * j) * 17 + (w * CPW + cc)] = (float)r[cc][j];
    __syncthreads();
    {
        const float* zb = z + (size_t)b * D * T + t0;
        float* ob = out + (size_t)b * D * T + t0;
        for (int rr = 0; rr < 32; ++rr) {
            int e = rr * 256 + tid;
            int d = e >> 4, c = e & 15;
            ob[(size_t)d * T + c] = zb[(size_t)d * T + c] - zt[d * 17 + c];
        }
    }

    // ---- per-block loss partial (wloss is wave-uniform) ----
    __syncthreads();
    double* wl = (double*)lds;
    if (l == 0) wl[w] = wloss;
    __syncthreads();
    if (tid == 0) wsl[blk] = (wl[0] + wl[1]) + (wl[2] + wl[3]);
}

__global__ void rvq_loss_reduce(const double* __restrict__ wsl,
                                float* __restrict__ out) {
    __shared__ double sm[4];
    int tid = threadIdx.x;
    double s = 0.0;
    for (int e = tid; e < NBLK; e += 256) s += wsl[e];
    for (int off = 32; off; off >>= 1) s += __shfl_xor(s, off, 64);
    if ((tid & 63) == 0) sm[tid >> 6] = s;
    __syncthreads();
    if (tid == 0) {
        double tot = ((sm[0] + sm[1]) + (sm[2] + sm[3])) * (1.0 / 262144.0);
        float* lossp = out + (size_t)B * D * T + (size_t)B * N * T + (size_t)B * N * CD * T;
        lossp[0] = (float)tot;   // commitment
        lossp[1] = (float)tot;   // codebook (identical in eval forward)
    }
}

extern "C" void kernel_launch(void* const* d_in, const int* in_sizes, int n_in,
                              void* d_out, int out_size, void* d_ws, size_t ws_size,
                              hipStream_t stream) {
    const float* z     = (const float*)d_in[0];
    const float* in_v  = (const float*)d_in[1];
    const float* in_g  = (const float*)d_in[2];
    const float* in_b  = (const float*)d_in[3];
    const float* out_v = (const float*)d_in[4];
    const float* out_g = (const float*)d_in[5];
    const float* out_b = (const float*)d_in[6];
    const float* cb    = (const float*)d_in[7];
    float* out  = (float*)d_out;
    double* ws  = (double*)d_ws;
    double* wsl = ws + 160000;   // loss partials

    rvq_prep<<<55, 256, 0, stream>>>(in_v, in_g, out_v, out_g, cb, ws);
    rvq_main<<<NBLK, 256, 65536, stream>>>(z, in_b, out_b, cb, ws, wsl, out);
    rvq_loss_reduce<<<1, 256, 0, stream>>>(wsl, out);
}

// Round 6
// 3051.034 us; speedup vs baseline: 1.4624x; 1.4624x over previous
//
#include <hip/hip_runtime.h>
#include <math.h>

// Problem constants (fixed by setup_inputs)
constexpr int B  = 8;
constexpr int D  = 512;
constexpr int T  = 4096;
constexpr int N  = 9;
constexpr int CS = 1024;
constexpr int CD = 8;

constexpr int TT  = 16;   // columns per block
constexpr int CPW = 4;    // columns per wave
constexpr int NBLK = 2048;

#define WN_EPS 1e-12

// ---------------- workspace layout (doubles) ----------------
// w_in_n  [N][CD][D]   : 36864
// w_out_n [N][D][CD]   : 36864
// cb_n    [N][CS][CD]  : 73728
// cb_sq   [N][CS]      : 9216
// loss partials at ws+160000 : NBLK doubles

__global__ void rvq_prep(const float* __restrict__ in_v,
                         const float* __restrict__ in_g,
                         const float* __restrict__ out_v,
                         const float* __restrict__ out_g,
                         const float* __restrict__ cb,
                         double* __restrict__ ws) {
    double* w_in_n  = ws;
    double* w_out_n = ws + N * CD * D;
    double* cb_n    = ws + 2 * N * CD * D;
    double* cb_sq   = cb_n + N * CS * CD;

    int blk = blockIdx.x;
    int tid = threadIdx.x;

    if (blk == 0) {
        int row = tid;                       // 72 rows of length 512
        if (row < N * CD) {
            const float* v = in_v + (size_t)row * D;
            double s = 0.0;
            for (int j = 0; j < D; ++j) { double x = (double)v[j]; s += x * x; }
            double denom = fmax(sqrt(s), WN_EPS);
            double g = (double)in_g[row];
            for (int j = 0; j < D; ++j)
                w_in_n[(size_t)row * D + j] = (g * (double)v[j]) / denom;
        }
    } else if (blk <= 18) {
        int row = (blk - 1) * 256 + tid;     // 4608 rows of length 8
        if (row < N * D) {
            const float* v = out_v + (size_t)row * CD;
            double s = 0.0;
            #pragma unroll
            for (int k = 0; k < CD; ++k) { double x = (double)v[k]; s += x * x; }
            double denom = fmax(sqrt(s), WN_EPS);
            double g = (double)out_g[row];
            #pragma unroll
            for (int k = 0; k < CD; ++k)
                w_out_n[(size_t)row * CD + k] = (g * (double)v[k]) / denom;
        }
    } else {
        int row = (blk - 19) * 256 + tid;    // 9216 rows of length 8
        if (row < N * CS) {
            const float* v = cb + (size_t)row * CD;
            double s = 0.0;
            #pragma unroll
            for (int k = 0; k < CD; ++k) { double x = (double)v[k]; s += x * x; }
            double denom = fmax(sqrt(s), WN_EPS);
            double sq = 0.0;
            #pragma unroll
            for (int k = 0; k < CD; ++k) {
                double e = (double)v[k] / denom;
                cb_n[(size_t)row * CD + k] = e;
                sq += e * e;
            }
            cb_sq[row] = sq;
        }
    }
}

// ---- cross-lane helpers (wave64); CTRL must be a literal ----
template<int CTRL>
__device__ inline double dpp_mov_f64(double x) {
    union { double d; int i[2]; } u, v;
    u.d = x;
    v.i[0] = __builtin_amdgcn_update_dpp(0, u.i[0], CTRL, 0xF, 0xF, false);
    v.i[1] = __builtin_amdgcn_update_dpp(0, u.i[1], CTRL, 0xF, 0xF, false);
    return v.d;
}
template<int CTRL>
__device__ inline int dpp_mov_i32(int x) {
    return __builtin_amdgcn_update_dpp(0, x, CTRL, 0xF, 0xF, false);
}
// full-wave sum, result in all lanes. Rounds: xor1, xor2, half-mirror (==xor4
// after quad rounds), mirror (==xor8), then shfl 16/32.
__device__ inline double wave_allsum_f64(double x) {
    x += dpp_mov_f64<0xB1>(x);   // quad_perm(1,0,3,2)
    x += dpp_mov_f64<0x4E>(x);   // quad_perm(2,3,0,1)
    x += dpp_mov_f64<0x141>(x);  // row_half_mirror
    x += dpp_mov_f64<0x140>(x);  // row_mirror
    x += __shfl_xor(x, 16, 64);
    x += __shfl_xor(x, 32, 64);
    return x;
}

template<int CTRL>
__device__ inline void argmin_round_dpp(double& bd, int& bi) {
    double od = dpp_mov_f64<CTRL>(bd);
    int    oi = dpp_mov_i32<CTRL>(bi);
    bool t = (od < bd) || (od == bd && oi < bi);
    bd = t ? od : bd;
    bi = t ? oi : bi;
}
__device__ inline void argmin_round_shfl(double& bd, int& bi, int off) {
    double od = __shfl_xor(bd, off, 64);
    int    oi = __shfl_xor(bi, off, 64);
    bool t = (od < bd) || (od == bd && oi < bi);
    bd = t ? od : bd;
    bi = t ? oi : bi;
}

// LDS codebook addressing: plane k at byte k*8192; element (c,k) at
// byte k*8192 + ((c*8) ^ ((k&3)<<5)). Bijective per plane; both the staging
// writes and the scan reads land on 16 distinct banks x 4 lanes = the b64 floor.
__device__ inline int cbl_off(int c, int k) {
    return k * 8192 + ((c * 8) ^ ((k & 3) << 5));
}

__global__ __launch_bounds__(256)
void rvq_main(const float* __restrict__ z,
              const float* __restrict__ in_b,
              const float* __restrict__ out_b,
              const float* __restrict__ cb,
              const double* __restrict__ ws,
              double* __restrict__ wsl,
              float* __restrict__ out) {
    const double* w_in_n  = ws;
    const double* w_out_n = ws + N * CD * D;
    const double* cb_n    = ws + 2 * N * CD * D;
    const double* cb_sq   = cb_n + N * CS * CD;

    extern __shared__ char lds[];            // 65536 B dynamic
    float* zt = (float*)lds;                 // [512][17] f32 transpose scratch

    const int tid = threadIdx.x;
    const int l   = tid & 63;
    const int w   = tid >> 6;
    const int blk = blockIdx.x;              // 2048
    const int b   = blk >> 8;                // 256 blocks per batch
    const int t0  = (blk & 255) * TT;
    const int tw  = t0 + w * CPW;            // this wave's first column

    // ---- transpose z into zt (coalesced global reads) ----
    {
        const float* zb = z + (size_t)b * D * T + t0;
        for (int rr = 0; rr < 32; ++rr) {
            int e = rr * 256 + tid;
            int d = e >> 4, c = e & 15;
            zt[d * 17 + c] = zb[(size_t)d * T + c];
        }
    }
    __syncthreads();

    // ---- residual in registers: r[cc][j] holds d = l + 64*j of column tw+cc ----
    double r[CPW][8];
    #pragma unroll
    for (int cc = 0; cc < CPW; ++cc)
        #pragma unroll
        for (int j = 0; j < 8; ++j)
            r[cc][j] = (double)zt[(l + 64 * j) * 17 + (w * CPW + cc)];
    __syncthreads();   // zt dead; lds becomes the codebook buffer

    double ze[CD][CPW];
    double wloss = 0.0;

    float* codes_out = out + (size_t)B * D * T;
    float* lat_out   = codes_out + (size_t)B * N * T;

    for (int i = 0; i < N; ++i) {
        // ---- stage codebook (f64, swizzled) into LDS ----
        {
            const double* src = cb_n + (size_t)i * CS * CD;
            for (int rr = 0; rr < 32; ++rr) {
                int e = rr * 256 + tid;      // e = c*8 + k
                int c = e >> 3, k = e & 7;
                *(double*)(lds + cbl_off(c, k)) = src[e];
            }
        }
        __syncthreads();

        // ---- in-proj: z_e[k][col] = sum_d w_in[k][d] * r[d][col] + b ----
        const double* Wi = w_in_n + (size_t)i * CD * D;
        #pragma unroll
        for (int k = 0; k < CD; ++k) {
            const double* wk = Wi + (size_t)k * D + l;
            double p0 = 0.0, p1 = 0.0, p2 = 0.0, p3 = 0.0;
            #pragma unroll
            for (int j = 0; j < 8; ++j) {
                double wv = wk[64 * j];
                p0 = fma(wv, r[0][j], p0);
                p1 = fma(wv, r[1][j], p1);
                p2 = fma(wv, r[2][j], p2);
                p3 = fma(wv, r[3][j], p3);
            }
            double bias = (double)in_b[i * CD + k];
            ze[k][0] = wave_allsum_f64(p0) + bias;
            ze[k][1] = wave_allsum_f64(p1) + bias;
            ze[k][2] = wave_allsum_f64(p2) + bias;
            ze[k][3] = wave_allsum_f64(p3) + bias;
        }

        // ---- latents (lane 0 of each wave writes 8 float4) ----
        if (l == 0) {
            #pragma unroll
            for (int k = 0; k < CD; ++k) {
                float4 v = make_float4((float)ze[k][0], (float)ze[k][1],
                                       (float)ze[k][2], (float)ze[k][3]);
                *(float4*)&lat_out[((size_t)b * N * CD + (size_t)i * CD + k) * T + tw] = v;
            }
        }

        // ---- per-column normalize constants ----
        double es[CPW], m2i[CPW];
        #pragma unroll
        for (int cc = 0; cc < CPW; ++cc) {
            double s = 0.0;
            #pragma unroll
            for (int k = 0; k < CD; ++k) s = fma(ze[k][cc], ze[k][cc], s);
            double denom = fmax(sqrt(s), WN_EPS);
            double inv = 1.0 / denom;
            es[cc]  = s * inv * inv;
            m2i[cc] = -2.0 * inv;
        }

        // ---- distance scan: lane l covers codes l + 64*g ----
        const double* Cq = cb_sq + (size_t)i * CS;
        double best[CPW];
        int    bcode[CPW];
        #pragma unroll
        for (int cc = 0; cc < CPW; ++cc) { best[cc] = __builtin_inf(); bcode[cc] = 0; }
        for (int g = 0; g < 16; ++g) {
            int c = l + 64 * g;
            double row[CD];
            #pragma unroll
            for (int k = 0; k < CD; ++k)
                row[k] = *(const double*)(lds + cbl_off(c, k));
            double cq = Cq[c];
            #pragma unroll
            for (int cc = 0; cc < CPW; ++cc) {
                double dot = 0.0;
                #pragma unroll
                for (int k = 0; k < CD; ++k) dot = fma(ze[k][cc], row[k], dot);
                double dist = fma(m2i[cc], dot, es[cc]) + cq;
                bool take = (dist < best[cc]);   // ascending c within lane: first-min
                best[cc]  = take ? dist : best[cc];
                bcode[cc] = take ? c : bcode[cc];
            }
        }

        // ---- argmin butterfly across 64 lanes (first-min tie-break) ----
        #pragma unroll
        for (int cc = 0; cc < CPW; ++cc) {
            double bd = best[cc]; int bi = bcode[cc];
            argmin_round_dpp<0xB1>(bd, bi);
            argmin_round_dpp<0x4E>(bd, bi);
            argmin_round_dpp<0x141>(bd, bi);
            argmin_round_dpp<0x140>(bd, bi);
            argmin_round_shfl(bd, bi, 16);
            argmin_round_shfl(bd, bi, 32);
            best[cc] = bd; bcode[cc] = bi;
        }

        // ---- codes (lane 0, one float4 per wave) ----
        if (l == 0) {
            float4 v = make_float4((float)bcode[0], (float)bcode[1],
                                   (float)bcode[2], (float)bcode[3]);
            *(float4*)&codes_out[((size_t)b * N + i) * T + tw] = v;
        }

        // ---- gather raw code + loss + straight-through (q overwrites ze) ----
        const float* Cb = cb + (size_t)i * CS * CD;
        #pragma unroll
        for (int cc = 0; cc < CPW; ++cc) {
            int ui = __builtin_amdgcn_readfirstlane(bcode[cc]);
            const float* crow = Cb + (size_t)ui * CD;
            #pragma unroll
            for (int k = 0; k < CD; ++k) {
                double cv = (double)crow[k];
                double zv = ze[k][cc];
                double df = zv - cv;
                wloss = fma(df, df, wloss);
                ze[k][cc] = zv + (cv - zv);    // z_e + (z_q_i - z_e)
            }
        }

        // ---- out-proj + residual update ----
        const double* Wo = w_out_n + (size_t)i * D * CD;
        #pragma unroll
        for (int j = 0; j < 8; ++j) {
            int d = l + 64 * j;
            const double* wr = Wo + (size_t)d * CD;
            double w0 = wr[0], w1 = wr[1], w2 = wr[2], w3 = wr[3];
            double w4 = wr[4], w5 = wr[5], w6 = wr[6], w7 = wr[7];
            double bias = (double)out_b[i * D + d];
            #pragma unroll
            for (int cc = 0; cc < CPW; ++cc) {
                double o = 0.0;
                o = fma(w0, ze[0][cc], o);
                o = fma(w1, ze[1][cc], o);
                o = fma(w2, ze[2][cc], o);
                o = fma(w3, ze[3][cc], o);
                o = fma(w4, ze[4][cc], o);
                o = fma(w5, ze[5][cc], o);
                o = fma(w6, ze[6][cc], o);
                o = fma(w7, ze[7][cc], o);
                o += bias;
                r[cc][j] -= o;
            }
        }
        __syncthreads();   // everyone done with this stage's LDS codebook
    }

    // ---- final: r -> zt (f32), then coalesced z_q = z - r ----
    #pragma unroll
    for (int cc = 0; cc < CPW; ++cc)
        #pragma unroll
        for (int j = 0; j < 8; ++j)
            zt[(l + 64 * j) * 17 + (w * CPW + cc)] = (float)r[cc][j];
    __syncthreads();
    {
        const float* zb = z + (size_t)b * D * T + t0;
        float* ob = out + (size_t)b * D * T + t0;
        for (int rr = 0; rr < 32; ++rr) {
            int e = rr * 256 + tid;
            int d = e >> 4, c = e & 15;
            ob[(size_t)d * T + c] = zb[(size_t)d * T + c] - zt[d * 17 + c];
        }
    }

    // ---- per-block loss partial (wloss is wave-uniform) ----
    __syncthreads();
    double* wl = (double*)lds;
    if (l == 0) wl[w] = wloss;
    __syncthreads();
    if (tid == 0) wsl[blk] = (wl[0] + wl[1]) + (wl[2] + wl[3]);
}

__global__ void rvq_loss_reduce(const double* __restrict__ wsl,
                                float* __restrict__ out) {
    __shared__ double sm[4];
    int tid = threadIdx.x;
    double s = 0.0;
    for (int e = tid; e < NBLK; e += 256) s += wsl[e];
    for (int off = 32; off; off >>= 1) s += __shfl_xor(s, off, 64);
    if ((tid & 63) == 0) sm[tid >> 6] = s;
    __syncthreads();
    if (tid == 0) {
        double tot = ((sm[0] + sm[1]) + (sm[2] + sm[3])) * (1.0 / 262144.0);
        float* lossp = out + (size_t)B * D * T + (size_t)B * N * T + (size_t)B * N * CD * T;
        lossp[0] = (float)tot;   // commitment
        lossp[1] = (float)tot;   // codebook (identical in eval forward)
    }
}

extern "C" void kernel_launch(void* const* d_in, const int* in_sizes, int n_in,
                              void* d_out, int out_size, void* d_ws, size_t ws_size,
                              hipStream_t stream) {
    const float* z     = (const float*)d_in[0];
    const float* in_v  = (const float*)d_in[1];
    const float* in_g  = (const float*)d_in[2];
    const float* in_b  = (const float*)d_in[3];
    const float* out_v = (const float*)d_in[4];
    const float* out_g = (const float*)d_in[5];
    const float* out_b = (const float*)d_in[6];
    const float* cb    = (const float*)d_in[7];
    float* out  = (float*)d_out;
    double* ws  = (double*)d_ws;
    double* wsl = ws + 160000;   // loss partials

    rvq_prep<<<55, 256, 0, stream>>>(in_v, in_g, out_v, out_g, cb, ws);
    rvq_main<<<NBLK, 256, 65536, stream>>>(z, in_b, out_b, cb, ws, wsl, out);
    rvq_loss_reduce<<<1, 256, 0, stream>>>(wsl, out);
}

// Round 7
// 2427.740 us; speedup vs baseline: 1.8379x; 1.2567x over previous
//
#include <hip/hip_runtime.h>
#include <math.h>

// Problem constants (fixed by setup_inputs)
constexpr int B  = 8;
constexpr int D  = 512;
constexpr int T  = 4096;
constexpr int N  = 9;
constexpr int CS = 1024;
constexpr int CD = 8;

constexpr int TT  = 16;   // columns per block
constexpr int CPW = 4;    // columns per wave
constexpr int NBLK = 2048;

#define WN_EPS 1e-12

// ---------------- workspace layout (doubles) ----------------
// w_in_n  [N][CD][D]   : 36864
// w_out_n [N][D][CD]   : 36864
// cb_n    [N][CS][CD]  : 73728
// cb_sq   [N][CS]      : 9216
// loss partials at ws+160000 : NBLK doubles

__global__ void rvq_prep(const float* __restrict__ in_v,
                         const float* __restrict__ in_g,
                         const float* __restrict__ out_v,
                         const float* __restrict__ out_g,
                         const float* __restrict__ cb,
                         double* __restrict__ ws) {
    double* w_in_n  = ws;
    double* w_out_n = ws + N * CD * D;
    double* cb_n    = ws + 2 * N * CD * D;
    double* cb_sq   = cb_n + N * CS * CD;

    int blk = blockIdx.x;
    int tid = threadIdx.x;

    if (blk == 0) {
        int row = tid;                       // 72 rows of length 512
        if (row < N * CD) {
            const float* v = in_v + (size_t)row * D;
            double s = 0.0;
            for (int j = 0; j < D; ++j) { double x = (double)v[j]; s += x * x; }
            double denom = fmax(sqrt(s), WN_EPS);
            double g = (double)in_g[row];
            for (int j = 0; j < D; ++j)
                w_in_n[(size_t)row * D + j] = (g * (double)v[j]) / denom;
        }
    } else if (blk <= 18) {
        int row = (blk - 1) * 256 + tid;     // 4608 rows of length 8
        if (row < N * D) {
            const float* v = out_v + (size_t)row * CD;
            double s = 0.0;
            #pragma unroll
            for (int k = 0; k < CD; ++k) { double x = (double)v[k]; s += x * x; }
            double denom = fmax(sqrt(s), WN_EPS);
            double g = (double)out_g[row];
            #pragma unroll
            for (int k = 0; k < CD; ++k)
                w_out_n[(size_t)row * CD + k] = (g * (double)v[k]) / denom;
        }
    } else {
        int row = (blk - 19) * 256 + tid;    // 9216 rows of length 8
        if (row < N * CS) {
            const float* v = cb + (size_t)row * CD;
            double s = 0.0;
            #pragma unroll
            for (int k = 0; k < CD; ++k) { double x = (double)v[k]; s += x * x; }
            double denom = fmax(sqrt(s), WN_EPS);
            double sq = 0.0;
            #pragma unroll
            for (int k = 0; k < CD; ++k) {
                double e = (double)v[k] / denom;
                cb_n[(size_t)row * CD + k] = e;
                sq += e * e;
            }
            cb_sq[row] = sq;
        }
    }
}

// ---- cross-lane helpers (wave64); CTRL must be a literal ----
template<int CTRL>
__device__ inline double dpp_mov_f64(double x) {
    union { double d; int i[2]; } u, v;
    u.d = x;
    v.i[0] = __builtin_amdgcn_update_dpp(0, u.i[0], CTRL, 0xF, 0xF, false);
    v.i[1] = __builtin_amdgcn_update_dpp(0, u.i[1], CTRL, 0xF, 0xF, false);
    return v.d;
}
template<int CTRL>
__device__ inline int dpp_mov_i32(int x) {
    return __builtin_amdgcn_update_dpp(0, x, CTRL, 0xF, 0xF, false);
}
// full-wave sum, result in all lanes. Rounds: xor1, xor2, half-mirror (==xor4
// after quad rounds), mirror (==xor8), then shfl 16/32.
__device__ inline double wave_allsum_f64(double x) {
    x += dpp_mov_f64<0xB1>(x);   // quad_perm(1,0,3,2)
    x += dpp_mov_f64<0x4E>(x);   // quad_perm(2,3,0,1)
    x += dpp_mov_f64<0x141>(x);  // row_half_mirror
    x += dpp_mov_f64<0x140>(x);  // row_mirror
    x += __shfl_xor(x, 16, 64);
    x += __shfl_xor(x, 32, 64);
    return x;
}

template<int CTRL>
__device__ inline void argmin_round_dpp(double& bd, int& bi) {
    double od = dpp_mov_f64<CTRL>(bd);
    int    oi = dpp_mov_i32<CTRL>(bi);
    bool t = (od < bd) || (od == bd && oi < bi);
    bd = t ? od : bd;
    bi = t ? oi : bi;
}
__device__ inline void argmin_round_shfl(double& bd, int& bi, int off) {
    double od = __shfl_xor(bd, off, 64);
    int    oi = __shfl_xor(bi, off, 64);
    bool t = (od < bd) || (od == bd && oi < bi);
    bd = t ? od : bd;
    bi = t ? oi : bi;
}

// LDS codebook addressing: plane k at byte k*8192; element (c,k) at
// byte k*8192 + ((c*8) ^ ((k&3)<<5)).
__device__ inline int cbl_off(int c, int k) {
    return k * 8192 + ((c * 8) ^ ((k & 3) << 5));
}

__global__ __launch_bounds__(256)
void rvq_main(const float* __restrict__ z,
              const float* __restrict__ in_b,
              const float* __restrict__ out_b,
              const float* __restrict__ cb,
              const double* __restrict__ ws,
              double* __restrict__ wsl,
              float* __restrict__ out) {
    const double* w_in_n  = ws;
    const double* w_out_n = ws + N * CD * D;
    const double* cb_n    = ws + 2 * N * CD * D;
    const double* cb_sq   = cb_n + N * CS * CD;

    extern __shared__ char lds[];            // 65536 B dynamic
    float* zt = (float*)lds;                 // [512][17] f32 transpose scratch

    const int tid = threadIdx.x;
    const int l   = tid & 63;
    const int w   = tid >> 6;
    const int blk = blockIdx.x;              // 2048
    const int b   = blk >> 8;                // 256 blocks per batch
    const int t0  = (blk & 255) * TT;
    const int tw  = t0 + w * CPW;            // this wave's first column

    // ---- transpose z into zt (coalesced global reads) ----
    {
        const float* zb = z + (size_t)b * D * T + t0;
        #pragma unroll 4
        for (int rr = 0; rr < 32; ++rr) {
            int e = rr * 256 + tid;
            int d = e >> 4, c = e & 15;
            zt[d * 17 + c] = zb[(size_t)d * T + c];
        }
    }
    __syncthreads();

    // ---- residual in registers: r[cc][j] holds d = l + 64*j of column tw+cc ----
    double r[CPW][8];
    #pragma unroll
    for (int cc = 0; cc < CPW; ++cc)
        #pragma unroll
        for (int j = 0; j < 8; ++j)
            r[cc][j] = (double)zt[(l + 64 * j) * 17 + (w * CPW + cc)];
    __syncthreads();   // zt dead; lds becomes the codebook buffer

    double ze[CD][CPW];
    double wloss = 0.0;

    float* codes_out = out + (size_t)B * D * T;
    float* lat_out   = codes_out + (size_t)B * N * T;

    for (int i = 0; i < N; ++i) {
        // ---- stage codebook (f64, swizzled) into LDS; cap in-flight loads ----
        {
            const double* src = cb_n + (size_t)i * CS * CD;
            #pragma unroll 2
            for (int rr = 0; rr < 32; ++rr) {
                int e = rr * 256 + tid;      // e = c*8 + k
                int c = e >> 3, k = e & 7;
                *(double*)(lds + cbl_off(c, k)) = src[e];
            }
        }
        __syncthreads();

        // ---- in-proj: z_e[k][col] = sum_d w_in[k][d] * r[d][col] + b ----
        const double* Wi = w_in_n + (size_t)i * CD * D;
        #pragma unroll 2
        for (int k = 0; k < CD; ++k) {
            const double* wk = Wi + (size_t)k * D + l;
            double p0 = 0.0, p1 = 0.0, p2 = 0.0, p3 = 0.0;
            #pragma unroll
            for (int j = 0; j < 8; ++j) {
                double wv = wk[64 * j];
                p0 = fma(wv, r[0][j], p0);
                p1 = fma(wv, r[1][j], p1);
                p2 = fma(wv, r[2][j], p2);
                p3 = fma(wv, r[3][j], p3);
            }
            double bias = (double)in_b[i * CD + k];
            ze[k][0] = wave_allsum_f64(p0) + bias;
            ze[k][1] = wave_allsum_f64(p1) + bias;
            ze[k][2] = wave_allsum_f64(p2) + bias;
            ze[k][3] = wave_allsum_f64(p3) + bias;
        }

        // ---- latents (lane 0 of each wave writes 8 float4) ----
        if (l == 0) {
            #pragma unroll
            for (int k = 0; k < CD; ++k) {
                float4 v = make_float4((float)ze[k][0], (float)ze[k][1],
                                       (float)ze[k][2], (float)ze[k][3]);
                *(float4*)&lat_out[((size_t)b * N * CD + (size_t)i * CD + k) * T + tw] = v;
            }
        }

        // ---- per-column normalize constants ----
        double es[CPW], m2i[CPW];
        #pragma unroll
        for (int cc = 0; cc < CPW; ++cc) {
            double s = 0.0;
            #pragma unroll
            for (int k = 0; k < CD; ++k) s = fma(ze[k][cc], ze[k][cc], s);
            double denom = fmax(sqrt(s), WN_EPS);
            double inv = 1.0 / denom;
            es[cc]  = s * inv * inv;
            m2i[cc] = -2.0 * inv;
        }

        // ---- distance scan: lane l covers codes l + 64*g ----
        const double* Cq = cb_sq + (size_t)i * CS;
        double best[CPW];
        int    bcode[CPW];
        #pragma unroll
        for (int cc = 0; cc < CPW; ++cc) { best[cc] = __builtin_inf(); bcode[cc] = 0; }
        #pragma unroll 1
        for (int g = 0; g < 16; ++g) {
            int c = l + 64 * g;
            double row[CD];
            #pragma unroll
            for (int k = 0; k < CD; ++k)
                row[k] = *(const double*)(lds + cbl_off(c, k));
            double cq = Cq[c];
            #pragma unroll
            for (int cc = 0; cc < CPW; ++cc) {
                double dot = 0.0;
                #pragma unroll
                for (int k = 0; k < CD; ++k) dot = fma(ze[k][cc], row[k], dot);
                double dist = fma(m2i[cc], dot, es[cc]) + cq;
                bool take = (dist < best[cc]);   // ascending c within lane: first-min
                best[cc]  = take ? dist : best[cc];
                bcode[cc] = take ? c : bcode[cc];
            }
        }

        // ---- argmin butterfly across 64 lanes (first-min tie-break) ----
        #pragma unroll
        for (int cc = 0; cc < CPW; ++cc) {
            double bd = best[cc]; int bi = bcode[cc];
            argmin_round_dpp<0xB1>(bd, bi);
            argmin_round_dpp<0x4E>(bd, bi);
            argmin_round_dpp<0x141>(bd, bi);
            argmin_round_dpp<0x140>(bd, bi);
            argmin_round_shfl(bd, bi, 16);
            argmin_round_shfl(bd, bi, 32);
            best[cc] = bd; bcode[cc] = bi;
        }

        // ---- codes (lane 0, one float4 per wave) ----
        if (l == 0) {
            float4 v = make_float4((float)bcode[0], (float)bcode[1],
                                   (float)bcode[2], (float)bcode[3]);
            *(float4*)&codes_out[((size_t)b * N + i) * T + tw] = v;
        }

        // ---- gather raw code + loss + straight-through (q overwrites ze) ----
        const float* Cb = cb + (size_t)i * CS * CD;
        #pragma unroll
        for (int cc = 0; cc < CPW; ++cc) {
            int ui = __builtin_amdgcn_readfirstlane(bcode[cc]);
            const float* crow = Cb + (size_t)ui * CD;
            #pragma unroll
            for (int k = 0; k < CD; ++k) {
                double cv = (double)crow[k];
                double zv = ze[k][cc];
                double df = zv - cv;
                wloss = fma(df, df, wloss);
                ze[k][cc] = zv + (cv - zv);    // z_e + (z_q_i - z_e)
            }
        }

        // ---- out-proj + residual update ----
        const double* Wo = w_out_n + (size_t)i * D * CD;
        #pragma unroll 2
        for (int j = 0; j < 8; ++j) {
            int d = l + 64 * j;
            const double* wr = Wo + (size_t)d * CD;
            double w0 = wr[0], w1 = wr[1], w2 = wr[2], w3 = wr[3];
            double w4 = wr[4], w5 = wr[5], w6 = wr[6], w7 = wr[7];
            double bias = (double)out_b[i * D + d];
            #pragma unroll
            for (int cc = 0; cc < CPW; ++cc) {
                double o = 0.0;
                o = fma(w0, ze[0][cc], o);
                o = fma(w1, ze[1][cc], o);
                o = fma(w2, ze[2][cc], o);
                o = fma(w3, ze[3][cc], o);
                o = fma(w4, ze[4][cc], o);
                o = fma(w5, ze[5][cc], o);
                o = fma(w6, ze[6][cc], o);
                o = fma(w7, ze[7][cc], o);
                o += bias;
                r[cc][j] -= o;
            }
        }
        __syncthreads();   // everyone done with this stage's LDS codebook
    }

    // ---- final: r -> zt (f32), then coalesced z_q = z - r ----
    #pragma unroll
    for (int cc = 0; cc < CPW; ++cc)
        #pragma unroll
        for (int j = 0; j < 8; ++j)
            zt[(l + 64 * j) * 17 + (w * CPW + cc)] = (float)r[cc][j];
    __syncthreads();
    {
        const float* zb = z + (size_t)b * D * T + t0;
        float* ob = out + (size_t)b * D * T + t0;
        #pragma unroll 4
        for (int rr = 0; rr < 32; ++rr) {
            int e = rr * 256 + tid;
            int d = e >> 4, c = e & 15;
            ob[(size_t)d * T + c] = zb[(size_t)d * T + c] - zt[d * 17 + c];
        }
    }

    // ---- per-block loss partial (wloss is wave-uniform) ----
    __syncthreads();
    double* wl = (double*)lds;
    if (l == 0) wl[w] = wloss;
    __syncthreads();
    if (tid == 0) wsl[blk] = (wl[0] + wl[1]) + (wl[2] + wl[3]);
}

__global__ void rvq_loss_reduce(const double* __restrict__ wsl,
                                float* __restrict__ out) {
    __shared__ double sm[4];
    int tid = threadIdx.x;
    double s = 0.0;
    for (int e = tid; e < NBLK; e += 256) s += wsl[e];
    for (int off = 32; off; off >>= 1) s += __shfl_xor(s, off, 64);
    if ((tid & 63) == 0) sm[tid >> 6] = s;
    __syncthreads();
    if (tid == 0) {
        double tot = ((sm[0] + sm[1]) + (sm[2] + sm[3])) * (1.0 / 262144.0);
        float* lossp = out + (size_t)B * D * T + (size_t)B * N * T + (size_t)B * N * CD * T;
        lossp[0] = (float)tot;   // commitment
        lossp[1] = (float)tot;   // codebook (identical in eval forward)
    }
}

extern "C" void kernel_launch(void* const* d_in, const int* in_sizes, int n_in,
                              void* d_out, int out_size, void* d_ws, size_t ws_size,
                              hipStream_t stream) {
    const float* z     = (const float*)d_in[0];
    const float* in_v  = (const float*)d_in[1];
    const float* in_g  = (const float*)d_in[2];
    const float* in_b  = (const float*)d_in[3];
    const float* out_v = (const float*)d_in[4];
    const float* out_g = (const float*)d_in[5];
    const float* out_b = (const float*)d_in[6];
    const float* cb    = (const float*)d_in[7];
    float* out  = (float*)d_out;
    double* ws  = (double*)d_ws;
    double* wsl = ws + 160000;   // loss partials

    rvq_prep<<<55, 256, 0, stream>>>(in_v, in_g, out_v, out_g, cb, ws);
    rvq_main<<<NBLK, 256, 65536, stream>>>(z, in_b, out_b, cb, ws, wsl, out);
    rvq_loss_reduce<<<1, 256, 0, stream>>>(wsl, out);
}

// Round 8
// 2079.550 us; speedup vs baseline: 2.1456x; 1.1674x over previous
//
#include <hip/hip_runtime.h>
#include <math.h>

// Problem constants (fixed by setup_inputs)
constexpr int B  = 8;
constexpr int D  = 512;
constexpr int T  = 4096;
constexpr int N  = 9;
constexpr int CS = 1024;
constexpr int CD = 8;

constexpr int TT  = 16;   // columns per block
constexpr int CPW = 2;    // columns per wave (8 waves/block)
constexpr int NBLK = 2048;

#define WN_EPS 1e-12

// ---------------- workspace layout (doubles) ----------------
// w_in_n  [N][CD][D]   : 36864
// w_out_n [N][D][CD]   : 36864
// cb_n    [N][CS][CD]  : 73728
// cb_sq   [N][CS]      : 9216
// loss partials at ws+160000 : NBLK doubles

__global__ void rvq_prep(const float* __restrict__ in_v,
                         const float* __restrict__ in_g,
                         const float* __restrict__ out_v,
                         const float* __restrict__ out_g,
                         const float* __restrict__ cb,
                         double* __restrict__ ws) {
    double* w_in_n  = ws;
    double* w_out_n = ws + N * CD * D;
    double* cb_n    = ws + 2 * N * CD * D;
    double* cb_sq   = cb_n + N * CS * CD;

    int blk = blockIdx.x;
    int tid = threadIdx.x;

    if (blk == 0) {
        int row = tid;                       // 72 rows of length 512
        if (row < N * CD) {
            const float* v = in_v + (size_t)row * D;
            double s = 0.0;
            for (int j = 0; j < D; ++j) { double x = (double)v[j]; s += x * x; }
            double denom = fmax(sqrt(s), WN_EPS);
            double g = (double)in_g[row];
            for (int j = 0; j < D; ++j)
                w_in_n[(size_t)row * D + j] = (g * (double)v[j]) / denom;
        }
    } else if (blk <= 18) {
        int row = (blk - 1) * 256 + tid;     // 4608 rows of length 8
        if (row < N * D) {
            const float* v = out_v + (size_t)row * CD;
            double s = 0.0;
            #pragma unroll
            for (int k = 0; k < CD; ++k) { double x = (double)v[k]; s += x * x; }
            double denom = fmax(sqrt(s), WN_EPS);
            double g = (double)out_g[row];
            #pragma unroll
            for (int k = 0; k < CD; ++k)
                w_out_n[(size_t)row * CD + k] = (g * (double)v[k]) / denom;
        }
    } else {
        int row = (blk - 19) * 256 + tid;    // 9216 rows of length 8
        if (row < N * CS) {
            const float* v = cb + (size_t)row * CD;
            double s = 0.0;
            #pragma unroll
            for (int k = 0; k < CD; ++k) { double x = (double)v[k]; s += x * x; }
            double denom = fmax(sqrt(s), WN_EPS);
            double sq = 0.0;
            #pragma unroll
            for (int k = 0; k < CD; ++k) {
                double e = (double)v[k] / denom;
                cb_n[(size_t)row * CD + k] = e;
                sq += e * e;
            }
            cb_sq[row] = sq;
        }
    }
}

// ---- cross-lane helpers (wave64); CTRL must be a literal ----
template<int CTRL>
__device__ inline double dpp_mov_f64(double x) {
    union { double d; int i[2]; } u, v;
    u.d = x;
    v.i[0] = __builtin_amdgcn_update_dpp(0, u.i[0], CTRL, 0xF, 0xF, false);
    v.i[1] = __builtin_amdgcn_update_dpp(0, u.i[1], CTRL, 0xF, 0xF, false);
    return v.d;
}
template<int CTRL>
__device__ inline int dpp_mov_i32(int x) {
    return __builtin_amdgcn_update_dpp(0, x, CTRL, 0xF, 0xF, false);
}
// full-wave sum, result in all lanes.
__device__ inline double wave_allsum_f64(double x) {
    x += dpp_mov_f64<0xB1>(x);   // quad_perm(1,0,3,2)
    x += dpp_mov_f64<0x4E>(x);   // quad_perm(2,3,0,1)
    x += dpp_mov_f64<0x141>(x);  // row_half_mirror
    x += dpp_mov_f64<0x140>(x);  // row_mirror
    x += __shfl_xor(x, 16, 64);
    x += __shfl_xor(x, 32, 64);
    return x;
}

template<int CTRL>
__device__ inline void argmin_round_dpp(double& bd, int& bi) {
    double od = dpp_mov_f64<CTRL>(bd);
    int    oi = dpp_mov_i32<CTRL>(bi);
    bool t = (od < bd) || (od == bd && oi < bi);
    bd = t ? od : bd;
    bi = t ? oi : bi;
}
__device__ inline void argmin_round_shfl(double& bd, int& bi, int off) {
    double od = __shfl_xor(bd, off, 64);
    int    oi = __shfl_xor(bi, off, 64);
    bool t = (od < bd) || (od == bd && oi < bi);
    bd = t ? od : bd;
    bi = t ? oi : bi;
}

// LDS codebook addressing: plane k at byte k*8192; element (c,k) at
// byte k*8192 + ((c*8) ^ ((k&3)<<5)).
__device__ inline int cbl_off(int c, int k) {
    return k * 8192 + ((c * 8) ^ ((k & 3) << 5));
}

__global__ __launch_bounds__(512)
void rvq_main(const float* __restrict__ z,
              const float* __restrict__ in_b,
              const float* __restrict__ out_b,
              const float* __restrict__ cb,
              const double* __restrict__ ws,
              double* __restrict__ wsl,
              float* __restrict__ out) {
    const double* w_in_n  = ws;
    const double* w_out_n = ws + N * CD * D;
    const double* cb_n    = ws + 2 * N * CD * D;
    const double* cb_sq   = cb_n + N * CS * CD;

    extern __shared__ char lds[];            // 65536 B dynamic
    float* zt = (float*)lds;                 // [512][17] f32 transpose scratch

    const int tid = threadIdx.x;             // 512 threads = 8 waves
    const int l   = tid & 63;
    const int w   = tid >> 6;
    const int blk = blockIdx.x;              // 2048
    const int b   = blk >> 8;                // 256 blocks per batch
    const int t0  = (blk & 255) * TT;
    const int tw  = t0 + w * CPW;            // this wave's first column

    // ---- transpose z into zt (coalesced global reads) ----
    {
        const float* zb = z + (size_t)b * D * T + t0;
        #pragma unroll 4
        for (int rr = 0; rr < 16; ++rr) {
            int e = rr * 512 + tid;
            int d = e >> 4, c = e & 15;
            zt[d * 17 + c] = zb[(size_t)d * T + c];
        }
    }
    __syncthreads();

    // ---- residual in registers: r[cc][j] holds d = l + 64*j of column tw+cc ----
    double r[CPW][8];
    #pragma unroll
    for (int cc = 0; cc < CPW; ++cc)
        #pragma unroll
        for (int j = 0; j < 8; ++j)
            r[cc][j] = (double)zt[(l + 64 * j) * 17 + (w * CPW + cc)];
    __syncthreads();   // zt dead; lds becomes the codebook buffer

    double ze[CD][CPW];
    double wloss = 0.0;

    float* codes_out = out + (size_t)B * D * T;
    float* lat_out   = codes_out + (size_t)B * N * T;

    for (int i = 0; i < N; ++i) {
        // ---- stage codebook (f64, swizzled) into LDS ----
        {
            const double* src = cb_n + (size_t)i * CS * CD;
            #pragma unroll 2
            for (int rr = 0; rr < 16; ++rr) {
                int e = rr * 512 + tid;      // e = c*8 + k
                int c = e >> 3, k = e & 7;
                *(double*)(lds + cbl_off(c, k)) = src[e];
            }
        }
        __syncthreads();

        // ---- in-proj: z_e[k][col] = sum_d w_in[k][d] * r[d][col] + b ----
        const double* Wi = w_in_n + (size_t)i * CD * D;
        #pragma unroll 2
        for (int k = 0; k < CD; ++k) {
            const double* wk = Wi + (size_t)k * D + l;
            double p0 = 0.0, p1 = 0.0;
            #pragma unroll
            for (int j = 0; j < 8; ++j) {
                double wv = wk[64 * j];
                p0 = fma(wv, r[0][j], p0);
                p1 = fma(wv, r[1][j], p1);
            }
            double bias = (double)in_b[i * CD + k];
            ze[k][0] = wave_allsum_f64(p0) + bias;
            ze[k][1] = wave_allsum_f64(p1) + bias;
        }

        // ---- latents (lane 0 of each wave writes 8 float2) ----
        if (l == 0) {
            #pragma unroll
            for (int k = 0; k < CD; ++k) {
                float2 v = make_float2((float)ze[k][0], (float)ze[k][1]);
                *(float2*)&lat_out[((size_t)b * N * CD + (size_t)i * CD + k) * T + tw] = v;
            }
        }

        // ---- per-column normalize constants ----
        double es[CPW], m2i[CPW];
        #pragma unroll
        for (int cc = 0; cc < CPW; ++cc) {
            double s = 0.0;
            #pragma unroll
            for (int k = 0; k < CD; ++k) s = fma(ze[k][cc], ze[k][cc], s);
            double denom = fmax(sqrt(s), WN_EPS);
            double inv = 1.0 / denom;
            es[cc]  = s * inv * inv;
            m2i[cc] = -2.0 * inv;
        }

        // ---- distance scan: lane l covers codes l + 64*g ----
        const double* Cq = cb_sq + (size_t)i * CS;
        double best[CPW];
        int    bcode[CPW];
        #pragma unroll
        for (int cc = 0; cc < CPW; ++cc) { best[cc] = __builtin_inf(); bcode[cc] = 0; }
        #pragma unroll 1
        for (int g = 0; g < 16; ++g) {
            int c = l + 64 * g;
            double row[CD];
            #pragma unroll
            for (int k = 0; k < CD; ++k)
                row[k] = *(const double*)(lds + cbl_off(c, k));
            double cq = Cq[c];
            #pragma unroll
            for (int cc = 0; cc < CPW; ++cc) {
                double dot = 0.0;
                #pragma unroll
                for (int k = 0; k < CD; ++k) dot = fma(ze[k][cc], row[k], dot);
                double dist = fma(m2i[cc], dot, es[cc]) + cq;
                bool take = (dist < best[cc]);   // ascending c within lane: first-min
                best[cc]  = take ? dist : best[cc];
                bcode[cc] = take ? c : bcode[cc];
            }
        }

        // ---- argmin butterfly across 64 lanes (first-min tie-break) ----
        #pragma unroll
        for (int cc = 0; cc < CPW; ++cc) {
            double bd = best[cc]; int bi = bcode[cc];
            argmin_round_dpp<0xB1>(bd, bi);
            argmin_round_dpp<0x4E>(bd, bi);
            argmin_round_dpp<0x141>(bd, bi);
            argmin_round_dpp<0x140>(bd, bi);
            argmin_round_shfl(bd, bi, 16);
            argmin_round_shfl(bd, bi, 32);
            best[cc] = bd; bcode[cc] = bi;
        }

        // ---- codes (lane 0, one float2 per wave) ----
        if (l == 0) {
            float2 v = make_float2((float)bcode[0], (float)bcode[1]);
            *(float2*)&codes_out[((size_t)b * N + i) * T + tw] = v;
        }

        // ---- gather raw code + loss + straight-through (q overwrites ze) ----
        const float* Cb = cb + (size_t)i * CS * CD;
        #pragma unroll
        for (int cc = 0; cc < CPW; ++cc) {
            int ui = __builtin_amdgcn_readfirstlane(bcode[cc]);
            const float* crow = Cb + (size_t)ui * CD;
            #pragma unroll
            for (int k = 0; k < CD; ++k) {
                double cv = (double)crow[k];
                double zv = ze[k][cc];
                double df = zv - cv;
                wloss = fma(df, df, wloss);
                ze[k][cc] = zv + (cv - zv);    // z_e + (z_q_i - z_e)
            }
        }

        // ---- out-proj + residual update ----
        const double* Wo = w_out_n + (size_t)i * D * CD;
        #pragma unroll 2
        for (int j = 0; j < 8; ++j) {
            int d = l + 64 * j;
            const double* wr = Wo + (size_t)d * CD;
            double w0 = wr[0], w1 = wr[1], w2 = wr[2], w3 = wr[3];
            double w4 = wr[4], w5 = wr[5], w6 = wr[6], w7 = wr[7];
            double bias = (double)out_b[i * D + d];
            #pragma unroll
            for (int cc = 0; cc < CPW; ++cc) {
                double o = 0.0;
                o = fma(w0, ze[0][cc], o);
                o = fma(w1, ze[1][cc], o);
                o = fma(w2, ze[2][cc], o);
                o = fma(w3, ze[3][cc], o);
                o = fma(w4, ze[4][cc], o);
                o = fma(w5, ze[5][cc], o);
                o = fma(w6, ze[6][cc], o);
                o = fma(w7, ze[7][cc], o);
                o += bias;
                r[cc][j] -= o;
            }
        }
        __syncthreads();   // everyone done with this stage's LDS codebook
    }

    // ---- final: r -> zt (f32), then coalesced z_q = z - r ----
    #pragma unroll
    for (int cc = 0; cc < CPW; ++cc)
        #pragma unroll
        for (int j = 0; j < 8; ++j)
            zt[(l + 64 * j) * 17 + (w * CPW + cc)] = (float)r[cc][j];
    __syncthreads();
    {
        const float* zb = z + (size_t)b * D * T + t0;
        float* ob = out + (size_t)b * D * T + t0;
        #pragma unroll 4
        for (int rr = 0; rr < 16; ++rr) {
            int e = rr * 512 + tid;
            int d = e >> 4, c = e & 15;
            ob[(size_t)d * T + c] = zb[(size_t)d * T + c] - zt[d * 17 + c];
        }
    }

    // ---- per-block loss partial (wloss is wave-uniform) ----
    __syncthreads();
    double* wl = (double*)lds;
    if (l == 0) wl[w] = wloss;
    __syncthreads();
    if (tid == 0) {
        double s = 0.0;
        #pragma unroll
        for (int ww = 0; ww < 8; ++ww) s += wl[ww];
        wsl[blk] = s;
    }
}

__global__ void rvq_loss_reduce(const double* __restrict__ wsl,
                                float* __restrict__ out) {
    __shared__ double sm[4];
    int tid = threadIdx.x;
    double s = 0.0;
    for (int e = tid; e < NBLK; e += 256) s += wsl[e];
    for (int off = 32; off; off >>= 1) s += __shfl_xor(s, off, 64);
    if ((tid & 63) == 0) sm[tid >> 6] = s;
    __syncthreads();
    if (tid == 0) {
        double tot = ((sm[0] + sm[1]) + (sm[2] + sm[3])) * (1.0 / 262144.0);
        float* lossp = out + (size_t)B * D * T + (size_t)B * N * T + (size_t)B * N * CD * T;
        lossp[0] = (float)tot;   // commitment
        lossp[1] = (float)tot;   // codebook (identical in eval forward)
    }
}

extern "C" void kernel_launch(void* const* d_in, const int* in_sizes, int n_in,
                              void* d_out, int out_size, void* d_ws, size_t ws_size,
                              hipStream_t stream) {
    const float* z     = (const float*)d_in[0];
    const float* in_v  = (const float*)d_in[1];
    const float* in_g  = (const float*)d_in[2];
    const float* in_b  = (const float*)d_in[3];
    const float* out_v = (const float*)d_in[4];
    const float* out_g = (const float*)d_in[5];
    const float* out_b = (const float*)d_in[6];
    const float* cb    = (const float*)d_in[7];
    float* out  = (float*)d_out;
    double* ws  = (double*)d_ws;
    double* wsl = ws + 160000;   // loss partials

    rvq_prep<<<55, 256, 0, stream>>>(in_v, in_g, out_v, out_g, cb, ws);
    rvq_main<<<NBLK, 512, 65536, stream>>>(z, in_b, out_b, cb, ws, wsl, out);
    rvq_loss_reduce<<<1, 256, 0, stream>>>(wsl, out);
}